// Round 1
// baseline (373.167 us; speedup 1.0000x reference)
//
#include <hip/hip_runtime.h>

// Problem constants (fixed by the reference):
//   x:            [64, 30, 30, 1024] fp32   = 235,929,600 B
//   pattern_idx:  [64, 30, 30]       int32, values in [0, 64)
//   spatial_pe:   [30, 30, 512]      fp32   (~1.8 MB, L2-resident)
//   pattern_pe:   [64, 512]          fp32   (~131 KB, L1/L2-resident)
//   out = x + concat(spatial_pe[h,w,:], pattern_pe[idx[b,h,w],:])
//
// NOTE: do NOT derive the element count from out_size — its units proved to be
// bytes (the 944 MB poison fill == 4x logical output showed the previous
// kernel's n4 = out_size/4 was the FLOAT count, causing 4x redundant traffic
// over the padded allocation). Shapes are fixed, so hard-code them.
#define D4      256          // 1024 floats / 4 per float4
#define HALF4   128          // 512 floats / 4
#define HWPIX   900          // 30*30
#define NPIX    (64 * HWPIX) // 57,600 pixels
#define N4      (NPIX * D4)  // 14,745,600 float4s = 235,929,600 B

__global__ __launch_bounds__(256) void cpe_kernel(
    const float4* __restrict__ x,
    const int*    __restrict__ idx,
    const float4* __restrict__ spe,   // [900 * 128] float4
    const float4* __restrict__ ppe,   // [64  * 128] float4
    float4*       __restrict__ out)
{
    int g = blockIdx.x * blockDim.x + threadIdx.x;
    if (g >= N4) return;

    int c4  = g & (D4 - 1);   // float4 channel within pixel
    int pix = g >> 8;         // global pixel index (b*900 + h*30 + w)

    float4 xv = x[g];
    float4 pv;
    if (c4 < HALF4) {
        // spatial half: h*30+w == pix % 900 (H=W=MAX_GRID=30, full grid)
        int hw = pix % HWPIX;
        pv = spe[hw * HALF4 + c4];
    } else {
        // pattern half: gather by per-pixel index (wave-uniform, L2-resident)
        unsigned p = (unsigned)idx[pix] & 63u;   // ref applies % 64
        pv = ppe[p * HALF4 + (c4 - HALF4)];
    }

    out[g] = make_float4(xv.x + pv.x, xv.y + pv.y, xv.z + pv.z, xv.w + pv.w);
}

extern "C" void kernel_launch(void* const* d_in, const int* in_sizes, int n_in,
                              void* d_out, int out_size, void* d_ws, size_t ws_size,
                              hipStream_t stream) {
    const float4* x   = (const float4*)d_in[0];
    const int*    idx = (const int*)   d_in[1];
    const float4* spe = (const float4*)d_in[2];
    const float4* ppe = (const float4*)d_in[3];
    float4*       out = (float4*)      d_out;

    int block = 256;
    int grid  = (N4 + block - 1) / block;  // 57,600 blocks (one pixel each)
    cpe_kernel<<<grid, block, 0, stream>>>(x, idx, spe, ppe, out);
}

// Round 2
// 371.300 us; speedup vs baseline: 1.0050x; 1.0050x over previous
//
#include <hip/hip_runtime.h>

// Problem constants (fixed by the reference):
//   x:            [64, 30, 30, 1024] fp32   = 235,929,600 B   (streamed, read once)
//   pattern_idx:  [64, 30, 30]       int32, values in [0, 64) (block-uniform gather)
//   spatial_pe:   [30, 30, 512]      fp32   ~1.8 MB  (re-read 64x -> keep in L2)
//   pattern_pe:   [64, 512]          fp32   ~131 KB  (re-read ~900x -> keep in L2)
//   out = x + concat(spatial_pe[h,w,:], pattern_pe[idx[b,h,w],:])   (written once)
//
// Round-1 findings:
//   - out_size is the float ELEMENT count (58,982,400): round-0's hard-coding of
//     N4 was a no-op (dur_us unchanged 372.5 -> 373.2).
//   - cpe_kernel absent from rocprof top-5 (all 943.7MB fills @ ~145us) => the
//     kernel itself is <143us; dur_us=373 includes in-graph harness poison/restore.
//   - This round: nontemporal hints on the streaming x-load and out-store so L2
//     stays dedicated to the PE tables (the only reused data).
#define D4      256          // 1024 floats / 4 per float4
#define HALF4   128          // 512 floats / 4
#define HWPIX   900          // 30*30
#define NPIX    (64 * HWPIX) // 57,600 pixels
#define N4      (NPIX * D4)  // 14,745,600 float4s = 235,929,600 B

typedef float f32x4 __attribute__((ext_vector_type(4)));

__global__ __launch_bounds__(256) void cpe_kernel(
    const f32x4* __restrict__ x,
    const int*   __restrict__ idx,
    const f32x4* __restrict__ spe,   // [900 * 128] f32x4
    const f32x4* __restrict__ ppe,   // [64  * 128] f32x4
    f32x4*       __restrict__ out)
{
    int g = blockIdx.x * blockDim.x + threadIdx.x;
    if (g >= N4) return;

    int c4  = g & (D4 - 1);   // float4 channel within pixel (== threadIdx.x)
    int pix = g >> 8;         // global pixel index (== blockIdx.x; block-uniform)

    // Streaming load: x is touched exactly once -> nontemporal (nt) so it
    // doesn't evict the PE tables from L2.
    f32x4 xv = __builtin_nontemporal_load(&x[g]);

    f32x4 pv;
    if (c4 < HALF4) {
        // spatial half: h*30+w == pix % 900 (full 30x30 grid). Block-uniform
        // scalar math; table read stays CACHED (64x reuse across batch).
        int hw = pix % HWPIX;
        pv = spe[hw * HALF4 + c4];
    } else {
        // pattern half: idx[pix] is block-uniform -> scalar load; table read
        // stays CACHED (~900x reuse).
        unsigned p = (unsigned)idx[pix] & 63u;   // ref applies % 64
        pv = ppe[p * HALF4 + (c4 - HALF4)];
    }

    // Written once, never re-read in this dispatch -> nontemporal store
    // (avoids L2 write-allocate pollution on the 236 MB stream).
    f32x4 r = xv + pv;   // elementwise fp32 add, same order as reference
    __builtin_nontemporal_store(r, &out[g]);
}

extern "C" void kernel_launch(void* const* d_in, const int* in_sizes, int n_in,
                              void* d_out, int out_size, void* d_ws, size_t ws_size,
                              hipStream_t stream) {
    const f32x4* x   = (const f32x4*)d_in[0];
    const int*   idx = (const int*)  d_in[1];
    const f32x4* spe = (const f32x4*)d_in[2];
    const f32x4* ppe = (const f32x4*)d_in[3];
    f32x4*       out = (f32x4*)      d_out;

    int block = 256;
    int grid  = (N4 + block - 1) / block;  // 57,600 blocks (one pixel each)
    cpe_kernel<<<grid, block, 0, stream>>>(x, idx, spe, ppe, out);
}